// Round 13
// baseline (193.661 us; speedup 1.0000x reference)
//
#include <hip/hip_runtime.h>
#include <hip/hip_bf16.h>

#define BB   2
#define TT   512
#define NF   6
#define DD   32
#define HIDD 128
#define NHH  4
#define HDD  32
#define GHH  32
#define FDD  128
#define LL   (TT*NF)      // 3072
#define EPSF 1e-5f
#define NQT16 (LL/16)     // 192

typedef __attribute__((ext_vector_type(8))) short  bf16x8;
typedef __attribute__((ext_vector_type(4))) float  f32x4;

#define MFMA16x16x32(a,b,c) __builtin_amdgcn_mfma_f32_16x16x32_bf16(a,b,c,0,0,0)

__device__ __forceinline__ unsigned short bfh(float f) {
    union { __hip_bfloat16 b; unsigned short u; } cv;
    cv.b = __float2bfloat16(f);
    return cv.u;
}
__device__ __forceinline__ float bff(unsigned short u) {
    return __uint_as_float(((unsigned)u) << 16);
}
__device__ __forceinline__ unsigned pk_bf16(float a, float b) {
    union { __hip_bfloat162 h2; unsigned u; } cv;
    cv.h2 = __float22bfloat162_rn(make_float2(a, b));
    return cv.u;
}
__device__ __forceinline__ bf16x8 ld8(const unsigned short* p) {
    return *reinterpret_cast<const bf16x8*>(p);
}

// ---------------------------------------------------------------------------
// Kernel 1: gater + gated QKV. 4 tokens per block, 128 threads (2 waves),
// one output column per thread. Emits bf16 hi/lo splits: Qh/Ql/Kh/Kl
// token-major [bh][tok][32] (Q pre-scaled by 1/sqrt(32)), Vth/Vtl transposed
// [bh][dim][tok]. (unchanged from R11 — proven)
// ---------------------------------------------------------------------------
__global__ __launch_bounds__(128) void gate_qkv_kernel(
    const float* __restrict__ x,
    const float* __restrict__ g_ln_w, const float* __restrict__ g_ln_b,
    const float* __restrict__ g_w1,   const float* __restrict__ g_b1,
    const float* __restrict__ g_w2,   const float* __restrict__ g_b2,
    const float* __restrict__ q_w,    const float* __restrict__ q_b,
    const float* __restrict__ k_w,    const float* __restrict__ k_b,
    const float* __restrict__ v_w,    const float* __restrict__ v_b,
    unsigned short* __restrict__ Qh, unsigned short* __restrict__ Ql,
    unsigned short* __restrict__ Kh, unsigned short* __restrict__ Kl,
    unsigned short* __restrict__ Vth, unsigned short* __restrict__ Vtl)
{
    const int tok0 = blockIdx.x * 4;
    const int tid  = threadIdx.x;

    __shared__ float xs[4][DD];
    __shared__ float lns[4][DD];
    __shared__ float hs[4][GHH];
    __shared__ float gate_s[4];

    xs[tid >> 5][tid & 31] = x[(size_t)tok0 * DD + tid];
    __syncthreads();

    const int tk = (tid >> 5) & 1;
    const int d5 = tid & 31;
    if (tid < 64) {
        #pragma unroll
        for (int tt = 0; tt < 2; tt++) {
            int t = tt * 2 + tk;
            float xv = xs[t][d5];
            float s1 = xv, s2 = xv * xv;
            #pragma unroll
            for (int m = 16; m >= 1; m >>= 1) {
                s1 += __shfl_xor(s1, m, 32);
                s2 += __shfl_xor(s2, m, 32);
            }
            float mu  = s1 * (1.0f / DD);
            float var = s2 * (1.0f / DD) - mu * mu;
            float r   = rsqrtf(var + EPSF);
            lns[t][d5] = (xv - mu) * r * g_ln_w[d5] + g_ln_b[d5];
        }
    }
    __syncthreads();
    if (tid < 64) {
        #pragma unroll
        for (int tt = 0; tt < 2; tt++) {
            int t = tt * 2 + tk;
            float acc = g_b1[d5];
            #pragma unroll
            for (int d = 0; d < DD; d++) acc += lns[t][d] * g_w1[d * GHH + d5];
            hs[t][d5] = acc / (1.0f + __expf(-acc));
        }
    }
    __syncthreads();
    if (tid < 64) {
        #pragma unroll
        for (int tt = 0; tt < 2; tt++) {
            int t = tt * 2 + tk;
            float p = hs[t][d5] * g_w2[d5];
            #pragma unroll
            for (int m = 16; m >= 1; m >>= 1) p += __shfl_xor(p, m, 32);
            if (d5 == 0) gate_s[t] = 1.0f / (1.0f + __expf(-(p + g_b2[0])));
        }
    }
    __syncthreads();

    const int col = tid;
    float aq[4], ak[4], av[4];
    #pragma unroll
    for (int t = 0; t < 4; t++) { aq[t] = q_b[col]; ak[t] = k_b[col]; av[t] = v_b[col]; }
    #pragma unroll
    for (int d = 0; d < DD; d++) {
        float wq = q_w[d * HIDD + col];
        float wk = k_w[d * HIDD + col];
        float wv = v_w[d * HIDD + col];
        #pragma unroll
        for (int t = 0; t < 4; t++) {
            float xd = xs[t][d];
            aq[t] += xd * wq; ak[t] += xd * wk; av[t] += xd * wv;
        }
    }

    const int b    = tok0 / LL;
    const int l0   = tok0 - b * LL;
    const int head = col >> 5;
    const int d5c  = col & 31;
    const float scale = 0.17677669529663688f;   // 1/sqrt(32), folded into Q

    unsigned short vh[4], vl[4];
    #pragma unroll
    for (int t = 0; t < 4; t++) {
        const float g = gate_s[t];
        const size_t a = ((size_t)(b * NHH + head) * LL + l0 + t) * HDD + d5c;
        float qv = aq[t] * g * scale;
        unsigned short h = bfh(qv); Qh[a] = h; Ql[a] = bfh(qv - bff(h));
        float kv = ak[t] * g;
        h = bfh(kv); Kh[a] = h; Kl[a] = bfh(kv - bff(h));
        float vv = av[t] * g;
        h = bfh(vv); vh[t] = h; vl[t] = bfh(vv - bff(h));
    }
    const size_t vbase = ((size_t)(b * NHH + head) * HDD + d5c) * LL + l0;
    *(ushort4*)(Vth + vbase) = make_ushort4(vh[0], vh[1], vh[2], vh[3]);
    *(ushort4*)(Vtl + vbase) = make_ushort4(vl[0], vl[1], vl[2], vl[3]);
}

// ---------------------------------------------------------------------------
// Kernel 2: MFMA flash-attention partials — SOFTWARE-PIPELINED at the MFMA
// level. Iteration t: (1) issue K loads for tile t+1 and V loads for tile t;
// (2) softmax on S(t) [computed LAST iteration]; (3) compute S(t+1) from the
// just-loaded K (its L2 latency hid under softmax); (4) PV(t). So the exp/
// shuffle chain is the only exposed latency — score-MFMA latency hides under
// PV + next-iter loads, load latency hides under softmax. K registers live
// only within one iteration (no double buffer).
// Grid 1-D, bh = blockIdx.x & 7 (XCD-local K/V, FETCH 4.6 MB — R11 verified).
// Layout math identical to R9-R11 (incl. cross-quad l reduction).
// ---------------------------------------------------------------------------
__global__ __launch_bounds__(256) void attn_mfma(
    const unsigned short* __restrict__ Qh, const unsigned short* __restrict__ Ql,
    const unsigned short* __restrict__ Kh, const unsigned short* __restrict__ Kl,
    const unsigned short* __restrict__ Vth, const unsigned short* __restrict__ Vtl,
    float* __restrict__ P, int C, int NCH)
{
    const int lin = blockIdx.x;
    const int bh  = lin & 7;                    // XCD-local clustering
    const int jj  = lin >> 3;
    const int ch  = jj / (LL / 64);
    const int qt  = (LL / 64 - 1) - (jj % (LL / 64));   // heavy prefixes first
    const int j0c = C * ch;
    const int jmax_blk = ((qt * 64 + 63) / NF + 1) * NF;
    if (j0c >= jmax_blk) return;           // dead chunk, uniform exit

    const int tid  = threadIdx.x;
    const int w    = tid >> 6;
    const int lane = tid & 63;
    const int rr   = lane & 15;            // query row in 16 / V-dim / B n-index
    const int quad = lane >> 4;

    const int ig0   = qt * 64 + w * 16;
    const int ig    = ig0 + rr;
    const int jend  = (ig / NF + 1) * NF;
    const int jmaxw = ((ig0 + 15) / NF + 1) * NF;
    const int jminw = (ig0 / NF + 1) * NF;

    const int kend = min(jmaxw - j0c, C);
    if (kend <= 0) return;                 // dead wave (partial never read)

    const size_t hbT = (size_t)bh * LL;
    const size_t qo  = (hbT + ig) * HDD + quad * 8;
    const bf16x8 qfh = ld8(Qh + qo);
    const bf16x8 qfl = ld8(Ql + qo);

    // permuted local key for A-frag row m=rr: frag f -> key 8*(m>>2)+4f+(m&3)
    const int kloc0 = 8 * (rr >> 2) + (rr & 3);
    const int kloc1 = kloc0 + 4;

    const size_t vb0 = ((size_t)bh * HDD + rr)      * LL;
    const size_t vb1 = ((size_t)bh * HDD + rr + 16) * LL;

    f32x4 o0 = {0.f, 0.f, 0.f, 0.f};       // O^T dims quad*4+reg
    f32x4 o1 = {0.f, 0.f, 0.f, 0.f};       // O^T dims 16+quad*4+reg
    float m = -1e30f, l = 0.f;

    // 64-key tiles; C and LL are multiples of 64, so over-reads (incl. the
    // last iteration's clamped prefetch) stay inside [0, LL).
    const int ntile = (kend + 63) >> 6;
    const f32x4 z = {0.f, 0.f, 0.f, 0.f};

    // score MFMAs for one 64-key tile at key offset j (helper as a macro-ish
    // lambda so preheader and loop share one definition)
    auto scores = [&](int j, f32x4& sA0, f32x4& sA1, f32x4& sB0, f32x4& sB1) {
        const size_t kA0 = (hbT + j + kloc0) * HDD + quad * 8;
        const size_t kA1 = (hbT + j + kloc1) * HDD + quad * 8;
        const size_t kB0 = kA0 + (size_t)32 * HDD;
        const size_t kB1 = kA1 + (size_t)32 * HDD;
        bf16x8 a0h = ld8(Kh + kA0), a0l = ld8(Kl + kA0);
        bf16x8 a1h = ld8(Kh + kA1), a1l = ld8(Kl + kA1);
        bf16x8 b0h = ld8(Kh + kB0), b0l = ld8(Kl + kB0);
        bf16x8 b1h = ld8(Kh + kB1), b1l = ld8(Kl + kB1);
        sA0 = MFMA16x16x32(a0h, qfh, z);
        sA1 = MFMA16x16x32(a1h, qfh, z);
        sB0 = MFMA16x16x32(b0h, qfh, z);
        sB1 = MFMA16x16x32(b1h, qfh, z);
        sA0 = MFMA16x16x32(a0h, qfl, sA0);
        sA1 = MFMA16x16x32(a1h, qfl, sA1);
        sB0 = MFMA16x16x32(b0h, qfl, sB0);
        sB1 = MFMA16x16x32(b1h, qfl, sB1);
        sA0 = MFMA16x16x32(a0l, qfh, sA0);
        sA1 = MFMA16x16x32(a1l, qfh, sA1);
        sB0 = MFMA16x16x32(b0l, qfh, sB0);
        sB1 = MFMA16x16x32(b1l, qfh, sB1);
    };

    // preheader: scores for tile 0
    f32x4 sA0, sA1, sB0, sB1;
    scores(j0c, sA0, sA1, sB0, sB1);

    for (int kt = 0; kt < ntile; kt++) {
        const int j0 = j0c + (kt << 6);
        const int jn = j0c + (((kt + 1 < ntile) ? kt + 1 : kt) << 6);

        // ---- V loads for current tile (used after softmax, ~300cyc later) ----
        const size_t vA = j0 + quad * 8, vB = vA + 32;
        bf16x8 vA0h = ld8(Vth + vb0 + vA), vA0l = ld8(Vtl + vb0 + vA);
        bf16x8 vA1h = ld8(Vth + vb1 + vA), vA1l = ld8(Vtl + vb1 + vA);
        bf16x8 vB0h = ld8(Vth + vb0 + vB), vB0l = ld8(Vtl + vb0 + vB);
        bf16x8 vB1h = ld8(Vth + vb1 + vB), vB1l = ld8(Vtl + vb1 + vB);

        // ---- softmax on S(kt) (computed last iteration / preheader) ----
        // local key of element r: A0=8q+r, A1=8q+4+r, B0=32+8q+r, B1=36+8q+r
        float e[16], mx, ls, corr;
        if (j0 + 64 <= jminw) {
            f32x4 m4 = sA0;
            #pragma unroll
            for (int r2 = 0; r2 < 4; r2++)
                m4[r2] = fmaxf(fmaxf(m4[r2], sA1[r2]), fmaxf(sB0[r2], sB1[r2]));
            mx = fmaxf(fmaxf(m4[0], m4[1]), fmaxf(m4[2], m4[3]));
            mx = fmaxf(mx, __shfl_xor(mx, 16));
            mx = fmaxf(mx, __shfl_xor(mx, 32));
            mx = fmaxf(m, mx);
            corr = __expf(m - mx); m = mx;
            ls = 0.f;
            #pragma unroll
            for (int r2 = 0; r2 < 4; r2++) {
                float e0 = __expf(sA0[r2] - mx);
                float e1 = __expf(sA1[r2] - mx);
                float e2 = __expf(sB0[r2] - mx);
                float e3 = __expf(sB1[r2] - mx);
                e[r2] = e0; e[4 + r2] = e1; e[8 + r2] = e2; e[12 + r2] = e3;
                ls += (e0 + e1) + (e2 + e3);
            }
        } else {
            const int je = jend - j0;
            const int k0 = 8 * quad;
            float t[16];
            #pragma unroll
            for (int r2 = 0; r2 < 4; r2++) {
                t[r2]      = (k0 + r2          < je) ? sA0[r2] : -1e30f;
                t[4 + r2]  = (k0 + 4 + r2      < je) ? sA1[r2] : -1e30f;
                t[8 + r2]  = (32 + k0 + r2     < je) ? sB0[r2] : -1e30f;
                t[12 + r2] = (32 + k0 + 4 + r2 < je) ? sB1[r2] : -1e30f;
            }
            mx = t[0];
            #pragma unroll
            for (int i = 1; i < 16; i++) mx = fmaxf(mx, t[i]);
            mx = fmaxf(mx, __shfl_xor(mx, 16));
            mx = fmaxf(mx, __shfl_xor(mx, 32));
            mx = fmaxf(m, mx);
            corr = __expf(m - mx); m = mx;
            ls = 0.f;
            #pragma unroll
            for (int r2 = 0; r2 < 4; r2++) {
                float e0 = __expf(t[r2] - mx);
                float e1 = __expf(t[4 + r2] - mx);
                float e2 = __expf(t[8 + r2] - mx);
                float e3 = __expf(t[12 + r2] - mx);
                e0 = (k0 + r2          < je) ? e0 : 0.f;   // kill exp(0)=1
                e1 = (k0 + 4 + r2      < je) ? e1 : 0.f;
                e2 = (32 + k0 + r2     < je) ? e2 : 0.f;
                e3 = (32 + k0 + 4 + r2 < je) ? e3 : 0.f;
                e[r2] = e0; e[4 + r2] = e1; e[8 + r2] = e2; e[12 + r2] = e3;
                ls += (e0 + e1) + (e2 + e3);
            }
        }
        l = l * corr + ls;
        #pragma unroll
        for (int i = 0; i < 4; i++) { o0[i] *= corr; o1[i] *= corr; }

        // pack P^T B-operands: group A keys k=quad*8+j, group B same +32
        union { unsigned u[4]; bf16x8 v; } pbA, pbB;
        pbA.u[0] = pk_bf16(e[0],  e[1]);
        pbA.u[1] = pk_bf16(e[2],  e[3]);
        pbA.u[2] = pk_bf16(e[4],  e[5]);
        pbA.u[3] = pk_bf16(e[6],  e[7]);
        pbB.u[0] = pk_bf16(e[8],  e[9]);
        pbB.u[1] = pk_bf16(e[10], e[11]);
        pbB.u[2] = pk_bf16(e[12], e[13]);
        pbB.u[3] = pk_bf16(e[14], e[15]);

        // ---- S(kt+1): issue BEFORE PV so its MFMA latency hides under PV
        // and next iteration's loads; its K loads were issued above... (they
        // are inside scores(), placed here so the L2 latency they pay sits
        // under the softmax VALU chain just executed on S(kt)).
        f32x4 tA0, tA1, tB0, tB1;
        scores(jn, tA0, tA1, tB0, tB1);

        // ---- PV(kt) ----
        o0 = MFMA16x16x32(vA0h, pbA.v, o0);
        o1 = MFMA16x16x32(vA1h, pbA.v, o1);
        o0 = MFMA16x16x32(vB0h, pbB.v, o0);
        o1 = MFMA16x16x32(vB1h, pbB.v, o1);
        o0 = MFMA16x16x32(vA0l, pbA.v, o0);
        o1 = MFMA16x16x32(vA1l, pbA.v, o1);
        o0 = MFMA16x16x32(vB0l, pbB.v, o0);
        o1 = MFMA16x16x32(vB1l, pbB.v, o1);

        // rotate pipeline
        sA0 = tA0; sA1 = tA1; sB0 = tB0; sB1 = tB1;
    }

    // l holds only this lane's per-tile partials; quads share the same m
    // scale, so the row denominator is the cross-quad sum (R8 bug fix).
    l += __shfl_xor(l, 16);
    l += __shfl_xor(l, 32);

    // write chunk partial: P[bh][qt16][ch][row16][36]
    float* dst = P + ((((size_t)bh * NQT16 + (ig0 >> 4)) * NCH + ch) * 16 + rr) * 36;
    *(f32x4*)(dst + quad * 4)      = o0;   // dims quad*4 .. +3
    *(f32x4*)(dst + 16 + quad * 4) = o1;   // dims 16+quad*4 .. +3
    if (quad == 0) { dst[32] = m; dst[33] = l; }
}

// ---------------------------------------------------------------------------
// Kernel 3: chunk-merge (flash-decoding) + mean-pool + o-proj + LN + f-proj
// + SiLU. Block per (t, b), 128 threads. (unchanged — proven)
// ---------------------------------------------------------------------------
__global__ __launch_bounds__(128) void final_kernel(
    const float* __restrict__ P,
    const float* __restrict__ o_w,    const float* __restrict__ o_b,
    const float* __restrict__ f_ln_w, const float* __restrict__ f_ln_b,
    const float* __restrict__ f_w,    const float* __restrict__ f_b,
    float* __restrict__ out, int C, int NCH)
{
    const int t = blockIdx.x;
    const int b = blockIdx.y;
    const int d = threadIdx.x;     // 0..127
    const int h  = d >> 5;         // head
    const int hd = d & 31;         // dim within head
    const int bh = b * NHH + h;

    __shared__ float ms[HIDD];
    __shared__ float lnbuf[HIDD];
    __shared__ float w1[2], w2[2];

    const int jmax = (t + 1) * NF;
    const int nch  = min(NCH, (jmax + C - 1) / C);

    float acc = 0.0f;
    #pragma unroll
    for (int f = 0; f < NF; f++) {
        const int row = t * NF + f;
        const int qt16 = row >> 4;
        const int r    = row & 15;
        float M = -1e30f, L = 0.0f, O = 0.0f;
        for (int c = 0; c < nch; c++) {
            const float* pr = P + ((((size_t)bh * NQT16 + qt16) * NCH + c) * 16 + r) * 36;
            const float mc = pr[32], lc = pr[33], oc = pr[hd];
            const float mm = fmaxf(M, mc);
            const float sa = __expf(M - mm), sb = __expf(mc - mm);
            O = O * sa + oc * sb;
            L = L * sa + lc * sb;
            M = mm;
        }
        acc += O / L;
    }
    acc *= (1.0f / NF);
    ms[d] = acc;
    __syncthreads();

    float ov = o_b[d];
    for (int k = 0; k < HIDD; k++) ov += ms[k] * o_w[k * HIDD + d];

    float s1 = ov, s2 = ov * ov;
    #pragma unroll
    for (int m = 32; m >= 1; m >>= 1) { s1 += __shfl_xor(s1, m); s2 += __shfl_xor(s2, m); }
    if ((d & 63) == 0) { w1[d >> 6] = s1; w2[d >> 6] = s2; }
    __syncthreads();
    float S1 = w1[0] + w1[1], S2 = w2[0] + w2[1];
    float mu  = S1 * (1.0f / HIDD);
    float var = S2 * (1.0f / HIDD) - mu * mu;
    float r   = rsqrtf(var + EPSF);
    float lnv = (ov - mu) * r * f_ln_w[d] + f_ln_b[d];
    lnbuf[d] = lnv;
    __syncthreads();

    float fv = f_b[d];
    for (int k = 0; k < HIDD; k++) fv += lnbuf[k] * f_w[k * HIDD + d];
    fv = fv / (1.0f + __expf(-fv));

    out[((size_t)(b * TT + t)) * FDD + d] = fv;
}

// ---------------------------------------------------------------------------
extern "C" void kernel_launch(void* const* d_in, const int* in_sizes, int n_in,
                              void* d_out, int out_size, void* d_ws, size_t ws_size,
                              hipStream_t stream)
{
    const float* x      = (const float*)d_in[0];
    const float* g_ln_w = (const float*)d_in[1];
    const float* g_ln_b = (const float*)d_in[2];
    const float* g_w1   = (const float*)d_in[3];
    const float* g_b1   = (const float*)d_in[4];
    const float* g_w2   = (const float*)d_in[5];
    const float* g_b2   = (const float*)d_in[6];
    const float* q_w    = (const float*)d_in[7];
    const float* q_b    = (const float*)d_in[8];
    const float* k_w    = (const float*)d_in[9];
    const float* k_b    = (const float*)d_in[10];
    const float* v_w    = (const float*)d_in[11];
    const float* v_b    = (const float*)d_in[12];
    const float* o_w    = (const float*)d_in[13];
    const float* o_b    = (const float*)d_in[14];
    const float* f_ln_w = (const float*)d_in[15];
    const float* f_ln_b = (const float*)d_in[16];
    const float* f_w    = (const float*)d_in[17];
    const float* f_b    = (const float*)d_in[18];

    const size_t ntok = (size_t)BB * NHH * LL * HDD;     // 786432 bf16 elems/array
    unsigned short* Qh  = (unsigned short*)d_ws;
    unsigned short* Ql  = Qh  + ntok;
    unsigned short* Kh  = Ql  + ntok;
    unsigned short* Kl  = Kh  + ntok;
    unsigned short* Vth = Kl  + ntok;
    unsigned short* Vtl = Vth + ntok;
    float* Pw = (float*)(Vtl + ntok);                    // split-K partials

    // chunk count from available scratch (deterministic per ws_size);
    // C a multiple of 64 (LL is too) keeps 64-key-tile over-reads inside LL.
    const long long bf_floats = (long long)(6 * ntok) / 2;          // 2359296
    const long long unit = 8LL * NQT16 * 16 * 36;                   // 884736 fl/chunk
    long long avail = (long long)(ws_size / 4) - bf_floats - 4096;  // slack
    int NCH = (int)(avail / unit);
    if (NCH > 6) NCH = 6;
    if (NCH < 1) NCH = 1;
    const int C = 64 * ((LL + 64 * NCH - 1) / (64 * NCH));          // keys/chunk

    gate_qkv_kernel<<<(BB * LL) / 4, 128, 0, stream>>>(
        x, g_ln_w, g_ln_b, g_w1, g_b1, g_w2, g_b2,
        q_w, q_b, k_w, k_b, v_w, v_b, Qh, Ql, Kh, Kl, Vth, Vtl);

    attn_mfma<<<(LL / 64) * NCH * BB * NHH, 256, 0, stream>>>(
        Qh, Ql, Kh, Kl, Vth, Vtl, Pw, C, NCH);

    final_kernel<<<dim3(TT, BB), 128, 0, stream>>>(
        Pw, o_w, o_b, f_ln_w, f_ln_b, f_w, f_b, (float*)d_out, C, NCH);
}

// Round 14
// 166.325 us; speedup vs baseline: 1.1644x; 1.1644x over previous
//
#include <hip/hip_runtime.h>
#include <hip/hip_bf16.h>

#define BB   2
#define TT   512
#define NF   6
#define DD   32
#define HIDD 128
#define NHH  4
#define HDD  32
#define GHH  32
#define FDD  128
#define LL   (TT*NF)      // 3072
#define EPSF 1e-5f
#define NQT16 (LL/16)     // 192

typedef __attribute__((ext_vector_type(8))) short  bf16x8;
typedef __attribute__((ext_vector_type(4))) float  f32x4;

#define MFMA16x16x32(a,b,c) __builtin_amdgcn_mfma_f32_16x16x32_bf16(a,b,c,0,0,0)

__device__ __forceinline__ unsigned short bfh(float f) {
    union { __hip_bfloat16 b; unsigned short u; } cv;
    cv.b = __float2bfloat16(f);
    return cv.u;
}
__device__ __forceinline__ float bff(unsigned short u) {
    return __uint_as_float(((unsigned)u) << 16);
}
__device__ __forceinline__ unsigned pk_bf16(float a, float b) {
    union { __hip_bfloat162 h2; unsigned u; } cv;
    cv.h2 = __float22bfloat162_rn(make_float2(a, b));
    return cv.u;
}
__device__ __forceinline__ bf16x8 ld8(const unsigned short* p) {
    return *reinterpret_cast<const bf16x8*>(p);
}

// 12 frags for one 64-key tile: K hi/lo for 2 permuted frag rows x 2 key
// halves, plus V hi for 2 dim halves x 2 key halves (V-lo split dropped:
// bf16 V quantization costs ~0.2% of |O|, inside the error budget).
struct Frags {
    bf16x8 k0h, k0l, k1h, k1l;   // keys X = [j0, j0+32)
    bf16x8 k2h, k2l, k3h, k3l;   // keys Y = [j0+32, j0+64)
    bf16x8 v0, v1, v2, v3;       // V^T hi: (dims rr / rr+16) x (X / Y)
};

__device__ __forceinline__ void load_tile(
    const unsigned short* __restrict__ Kh, const unsigned short* __restrict__ Kl,
    const unsigned short* __restrict__ Vth,
    size_t hbT, int j0, int kloc0, int kloc1, int quad,
    size_t vb0, size_t vb1, Frags& f)
{
    const size_t kX0 = (hbT + j0 + kloc0) * HDD + quad * 8;
    const size_t kX1 = (hbT + j0 + kloc1) * HDD + quad * 8;
    const size_t kY0 = kX0 + (size_t)32 * HDD;
    const size_t kY1 = kX1 + (size_t)32 * HDD;
    f.k0h = ld8(Kh + kX0); f.k0l = ld8(Kl + kX0);
    f.k1h = ld8(Kh + kX1); f.k1l = ld8(Kl + kX1);
    f.k2h = ld8(Kh + kY0); f.k2l = ld8(Kl + kY0);
    f.k3h = ld8(Kh + kY1); f.k3l = ld8(Kl + kY1);
    const size_t vX = (size_t)j0 + quad * 8, vY = vX + 32;
    f.v0 = ld8(Vth + vb0 + vX);
    f.v1 = ld8(Vth + vb1 + vX);
    f.v2 = ld8(Vth + vb0 + vY);
    f.v3 = ld8(Vth + vb1 + vY);
}

// One tile's scores + online softmax + PV, updating (m, l, o0, o1).
// Local key of score element r: s0=8q+r, s1=8q+4+r, s2=32+8q+r, s3=36+8q+r.
__device__ __forceinline__ void compute_tile(
    const Frags& f, const bf16x8 qfh, const bf16x8 qfl,
    int j0, int jminw, int jend, int quad,
    float& m, float& l, f32x4& o0, f32x4& o1)
{
    const f32x4 z = {0.f, 0.f, 0.f, 0.f};
    f32x4 s0 = MFMA16x16x32(f.k0h, qfh, z);
    f32x4 s1 = MFMA16x16x32(f.k1h, qfh, z);
    f32x4 s2 = MFMA16x16x32(f.k2h, qfh, z);
    f32x4 s3 = MFMA16x16x32(f.k3h, qfh, z);
    s0 = MFMA16x16x32(f.k0h, qfl, s0);
    s1 = MFMA16x16x32(f.k1h, qfl, s1);
    s2 = MFMA16x16x32(f.k2h, qfl, s2);
    s3 = MFMA16x16x32(f.k3h, qfl, s3);
    s0 = MFMA16x16x32(f.k0l, qfh, s0);
    s1 = MFMA16x16x32(f.k1l, qfh, s1);
    s2 = MFMA16x16x32(f.k2l, qfh, s2);
    s3 = MFMA16x16x32(f.k3l, qfh, s3);

    float e[16], mx, ls, corr;
    if (j0 + 64 <= jminw) {
        // interior tile: all keys live for every row in the wave
        f32x4 m4 = s0;
        #pragma unroll
        for (int r2 = 0; r2 < 4; r2++)
            m4[r2] = fmaxf(fmaxf(m4[r2], s1[r2]), fmaxf(s2[r2], s3[r2]));
        mx = fmaxf(fmaxf(m4[0], m4[1]), fmaxf(m4[2], m4[3]));
        mx = fmaxf(mx, __shfl_xor(mx, 16));
        mx = fmaxf(mx, __shfl_xor(mx, 32));
        mx = fmaxf(m, mx);
        corr = __expf(m - mx); m = mx;
        ls = 0.f;
        #pragma unroll
        for (int r2 = 0; r2 < 4; r2++) {
            float e0 = __expf(s0[r2] - mx);
            float e1 = __expf(s1[r2] - mx);
            float e2 = __expf(s2[r2] - mx);
            float e3 = __expf(s3[r2] - mx);
            e[r2] = e0; e[4 + r2] = e1; e[8 + r2] = e2; e[12 + r2] = e3;
            ls += (e0 + e1) + (e2 + e3);
        }
    } else {
        // boundary tile: per-key prefix masking (mask pre-max, zero exp)
        const int je = jend - j0;
        const int k0 = 8 * quad;
        float t[16];
        #pragma unroll
        for (int r2 = 0; r2 < 4; r2++) {
            t[r2]      = (k0 + r2          < je) ? s0[r2] : -1e30f;
            t[4 + r2]  = (k0 + 4 + r2      < je) ? s1[r2] : -1e30f;
            t[8 + r2]  = (32 + k0 + r2     < je) ? s2[r2] : -1e30f;
            t[12 + r2] = (32 + k0 + 4 + r2 < je) ? s3[r2] : -1e30f;
        }
        mx = t[0];
        #pragma unroll
        for (int i = 1; i < 16; i++) mx = fmaxf(mx, t[i]);
        mx = fmaxf(mx, __shfl_xor(mx, 16));
        mx = fmaxf(mx, __shfl_xor(mx, 32));
        mx = fmaxf(m, mx);
        corr = __expf(m - mx); m = mx;
        ls = 0.f;
        #pragma unroll
        for (int r2 = 0; r2 < 4; r2++) {
            float e0 = __expf(t[r2] - mx);
            float e1 = __expf(t[4 + r2] - mx);
            float e2 = __expf(t[8 + r2] - mx);
            float e3 = __expf(t[12 + r2] - mx);
            e0 = (k0 + r2          < je) ? e0 : 0.f;   // kill exp(0)=1
            e1 = (k0 + 4 + r2      < je) ? e1 : 0.f;
            e2 = (32 + k0 + r2     < je) ? e2 : 0.f;
            e3 = (32 + k0 + 4 + r2 < je) ? e3 : 0.f;
            e[r2] = e0; e[4 + r2] = e1; e[8 + r2] = e2; e[12 + r2] = e3;
            ls += (e0 + e1) + (e2 + e3);
        }
    }
    l = l * corr + ls;
    #pragma unroll
    for (int i = 0; i < 4; i++) { o0[i] *= corr; o1[i] *= corr; }

    union { unsigned u[4]; bf16x8 v; } pbX, pbY;
    pbX.u[0] = pk_bf16(e[0],  e[1]);
    pbX.u[1] = pk_bf16(e[2],  e[3]);
    pbX.u[2] = pk_bf16(e[4],  e[5]);
    pbX.u[3] = pk_bf16(e[6],  e[7]);
    pbY.u[0] = pk_bf16(e[8],  e[9]);
    pbY.u[1] = pk_bf16(e[10], e[11]);
    pbY.u[2] = pk_bf16(e[12], e[13]);
    pbY.u[3] = pk_bf16(e[14], e[15]);

    o0 = MFMA16x16x32(f.v0, pbX.v, o0);
    o1 = MFMA16x16x32(f.v1, pbX.v, o1);
    o0 = MFMA16x16x32(f.v2, pbY.v, o0);
    o1 = MFMA16x16x32(f.v3, pbY.v, o1);
}

// ---------------------------------------------------------------------------
// Kernel 1: gater + gated QKV. 4 tokens per block, 128 threads (2 waves),
// one output column per thread. Emits bf16 hi/lo splits Qh/Ql/Kh/Kl
// token-major [bh][tok][32] (Q pre-scaled by 1/sqrt(32)), and V hi
// TRANSPOSED [bh][dim][tok] (V-lo split dropped this round).
// ---------------------------------------------------------------------------
__global__ __launch_bounds__(128) void gate_qkv_kernel(
    const float* __restrict__ x,
    const float* __restrict__ g_ln_w, const float* __restrict__ g_ln_b,
    const float* __restrict__ g_w1,   const float* __restrict__ g_b1,
    const float* __restrict__ g_w2,   const float* __restrict__ g_b2,
    const float* __restrict__ q_w,    const float* __restrict__ q_b,
    const float* __restrict__ k_w,    const float* __restrict__ k_b,
    const float* __restrict__ v_w,    const float* __restrict__ v_b,
    unsigned short* __restrict__ Qh, unsigned short* __restrict__ Ql,
    unsigned short* __restrict__ Kh, unsigned short* __restrict__ Kl,
    unsigned short* __restrict__ Vth)
{
    const int tok0 = blockIdx.x * 4;
    const int tid  = threadIdx.x;

    __shared__ float xs[4][DD];
    __shared__ float lns[4][DD];
    __shared__ float hs[4][GHH];
    __shared__ float gate_s[4];

    xs[tid >> 5][tid & 31] = x[(size_t)tok0 * DD + tid];
    __syncthreads();

    const int tk = (tid >> 5) & 1;
    const int d5 = tid & 31;
    if (tid < 64) {
        #pragma unroll
        for (int tt = 0; tt < 2; tt++) {
            int t = tt * 2 + tk;
            float xv = xs[t][d5];
            float s1 = xv, s2 = xv * xv;
            #pragma unroll
            for (int m = 16; m >= 1; m >>= 1) {
                s1 += __shfl_xor(s1, m, 32);
                s2 += __shfl_xor(s2, m, 32);
            }
            float mu  = s1 * (1.0f / DD);
            float var = s2 * (1.0f / DD) - mu * mu;
            float r   = rsqrtf(var + EPSF);
            lns[t][d5] = (xv - mu) * r * g_ln_w[d5] + g_ln_b[d5];
        }
    }
    __syncthreads();
    if (tid < 64) {
        #pragma unroll
        for (int tt = 0; tt < 2; tt++) {
            int t = tt * 2 + tk;
            float acc = g_b1[d5];
            #pragma unroll
            for (int d = 0; d < DD; d++) acc += lns[t][d] * g_w1[d * GHH + d5];
            hs[t][d5] = acc / (1.0f + __expf(-acc));
        }
    }
    __syncthreads();
    if (tid < 64) {
        #pragma unroll
        for (int tt = 0; tt < 2; tt++) {
            int t = tt * 2 + tk;
            float p = hs[t][d5] * g_w2[d5];
            #pragma unroll
            for (int m = 16; m >= 1; m >>= 1) p += __shfl_xor(p, m, 32);
            if (d5 == 0) gate_s[t] = 1.0f / (1.0f + __expf(-(p + g_b2[0])));
        }
    }
    __syncthreads();

    const int col = tid;
    float aq[4], ak[4], av[4];
    #pragma unroll
    for (int t = 0; t < 4; t++) { aq[t] = q_b[col]; ak[t] = k_b[col]; av[t] = v_b[col]; }
    #pragma unroll
    for (int d = 0; d < DD; d++) {
        float wq = q_w[d * HIDD + col];
        float wk = k_w[d * HIDD + col];
        float wv = v_w[d * HIDD + col];
        #pragma unroll
        for (int t = 0; t < 4; t++) {
            float xd = xs[t][d];
            aq[t] += xd * wq; ak[t] += xd * wk; av[t] += xd * wv;
        }
    }

    const int b    = tok0 / LL;
    const int l0   = tok0 - b * LL;
    const int head = col >> 5;
    const int d5c  = col & 31;
    const float scale = 0.17677669529663688f;   // 1/sqrt(32), folded into Q

    unsigned short vh[4];
    #pragma unroll
    for (int t = 0; t < 4; t++) {
        const float g = gate_s[t];
        const size_t a = ((size_t)(b * NHH + head) * LL + l0 + t) * HDD + d5c;
        float qv = aq[t] * g * scale;
        unsigned short h = bfh(qv); Qh[a] = h; Ql[a] = bfh(qv - bff(h));
        float kv = ak[t] * g;
        h = bfh(kv); Kh[a] = h; Kl[a] = bfh(kv - bff(h));
        vh[t] = bfh(av[t] * g);
    }
    const size_t vbase = ((size_t)(b * NHH + head) * HDD + d5c) * LL + l0;
    *(ushort4*)(Vth + vbase) = make_ushort4(vh[0], vh[1], vh[2], vh[3]);
}

// ---------------------------------------------------------------------------
// Kernel 2: MFMA flash-attention partials — DUAL-STREAM ILP. Each wave
// processes two tiles per loop iteration with fully independent online-
// softmax states (A = even tiles, B = odd tiles), merged once at the end
// (flash-decoding math). Both tiles' 24 loads issue before either stream's
// first waitcnt: since waves issue in order, this is the only structure
// that guarantees stream B's loads are in flight while stream A stalls —
// the compiler cannot merge the chains (unlike R10/R12's prefetch, which
// it sank). Grid 1-D, bh = blockIdx.x & 7 (XCD-local K/V — R11 verified
// FETCH 24.6 -> 4.6 MB). Layout math identical to R9-R12.
// ---------------------------------------------------------------------------
__global__ __launch_bounds__(256) void attn_mfma(
    const unsigned short* __restrict__ Qh, const unsigned short* __restrict__ Ql,
    const unsigned short* __restrict__ Kh, const unsigned short* __restrict__ Kl,
    const unsigned short* __restrict__ Vth,
    float* __restrict__ P, int C, int NCH)
{
    const int lin = blockIdx.x;
    const int bh  = lin & 7;                    // XCD-local clustering
    const int jj  = lin >> 3;
    const int ch  = jj / (LL / 64);
    const int qt  = (LL / 64 - 1) - (jj % (LL / 64));   // heavy prefixes first
    const int j0c = C * ch;
    const int jmax_blk = ((qt * 64 + 63) / NF + 1) * NF;
    if (j0c >= jmax_blk) return;           // dead chunk, uniform exit

    const int tid  = threadIdx.x;
    const int w    = tid >> 6;
    const int lane = tid & 63;
    const int rr   = lane & 15;            // query row in 16 / V-dim / B n-index
    const int quad = lane >> 4;

    const int ig0   = qt * 64 + w * 16;
    const int ig    = ig0 + rr;
    const int jend  = (ig / NF + 1) * NF;
    const int jmaxw = ((ig0 + 15) / NF + 1) * NF;
    const int jminw = (ig0 / NF + 1) * NF;

    const int kend = min(jmaxw - j0c, C);
    if (kend <= 0) return;                 // dead wave (partial never read)

    const size_t hbT = (size_t)bh * LL;
    const size_t qo  = (hbT + ig) * HDD + quad * 8;
    const bf16x8 qfh = ld8(Qh + qo);
    const bf16x8 qfl = ld8(Ql + qo);

    // permuted local key for A-frag row m=rr: frag f -> key 8*(m>>2)+4f+(m&3)
    const int kloc0 = 8 * (rr >> 2) + (rr & 3);
    const int kloc1 = kloc0 + 4;

    const size_t vb0 = ((size_t)bh * HDD + rr)      * LL;
    const size_t vb1 = ((size_t)bh * HDD + rr + 16) * LL;

    f32x4 oA0 = {0.f,0.f,0.f,0.f}, oA1 = {0.f,0.f,0.f,0.f};
    f32x4 oB0 = {0.f,0.f,0.f,0.f}, oB1 = {0.f,0.f,0.f,0.f};
    float mA = -1e30f, lA = 0.f, mB = -1e30f, lB = 0.f;

    // 64-key tiles; C and LL are multiples of 64, so over-reads (incl. the
    // clamped duplicate B-load on an odd tail) stay inside [0, LL).
    const int ntile = (kend + 63) >> 6;

    for (int i = 0; i < ntile; i += 2) {
        const int  j0A  = j0c + (i << 6);
        const bool hasB = (i + 1 < ntile);
        const int  j0B  = j0c + ((hasB ? i + 1 : i) << 6);  // clamp: load-only dup

        Frags fA, fB;
        load_tile(Kh, Kl, Vth, hbT, j0A, kloc0, kloc1, quad, vb0, vb1, fA);
        load_tile(Kh, Kl, Vth, hbT, j0B, kloc0, kloc1, quad, vb0, vb1, fB);

        compute_tile(fA, qfh, qfl, j0A, jminw, jend, quad, mA, lA, oA0, oA1);
        if (hasB)
            compute_tile(fB, qfh, qfl, j0B, jminw, jend, quad, mB, lB, oB0, oB1);
    }

    // merge the two streams (flash-decoding): per-lane, same quad structure.
    // If stream B never ran, mB=-1e30 -> wb=0 and it contributes nothing.
    const float mm = fmaxf(mA, mB);
    const float wa = __expf(mA - mm), wb = __expf(mB - mm);
    float l = lA * wa + lB * wb;
    f32x4 o0, o1;
    #pragma unroll
    for (int i = 0; i < 4; i++) {
        o0[i] = oA0[i] * wa + oB0[i] * wb;
        o1[i] = oA1[i] * wa + oB1[i] * wb;
    }

    // l holds only this lane's per-tile partials; quads share the same m
    // scale, so the row denominator is the cross-quad sum (R8 bug fix).
    l += __shfl_xor(l, 16);
    l += __shfl_xor(l, 32);

    // write chunk partial: P[bh][qt16][ch][row16][36]
    float* dst = P + ((((size_t)bh * NQT16 + (ig0 >> 4)) * NCH + ch) * 16 + rr) * 36;
    *(f32x4*)(dst + quad * 4)      = o0;   // dims quad*4 .. +3
    *(f32x4*)(dst + 16 + quad * 4) = o1;   // dims 16+quad*4 .. +3
    if (quad == 0) { dst[32] = mm; dst[33] = l; }
}

// ---------------------------------------------------------------------------
// Kernel 3: chunk-merge (flash-decoding) + mean-pool + o-proj + LN + f-proj
// + SiLU. Block per (t, b), 128 threads. (unchanged — proven)
// ---------------------------------------------------------------------------
__global__ __launch_bounds__(128) void final_kernel(
    const float* __restrict__ P,
    const float* __restrict__ o_w,    const float* __restrict__ o_b,
    const float* __restrict__ f_ln_w, const float* __restrict__ f_ln_b,
    const float* __restrict__ f_w,    const float* __restrict__ f_b,
    float* __restrict__ out, int C, int NCH)
{
    const int t = blockIdx.x;
    const int b = blockIdx.y;
    const int d = threadIdx.x;     // 0..127
    const int h  = d >> 5;         // head
    const int hd = d & 31;         // dim within head
    const int bh = b * NHH + h;

    __shared__ float ms[HIDD];
    __shared__ float lnbuf[HIDD];
    __shared__ float w1[2], w2[2];

    const int jmax = (t + 1) * NF;
    const int nch  = min(NCH, (jmax + C - 1) / C);

    float acc = 0.0f;
    #pragma unroll
    for (int f = 0; f < NF; f++) {
        const int row = t * NF + f;
        const int qt16 = row >> 4;
        const int r    = row & 15;
        float M = -1e30f, L = 0.0f, O = 0.0f;
        for (int c = 0; c < nch; c++) {
            const float* pr = P + ((((size_t)bh * NQT16 + qt16) * NCH + c) * 16 + r) * 36;
            const float mc = pr[32], lc = pr[33], oc = pr[hd];
            const float mm = fmaxf(M, mc);
            const float sa = __expf(M - mm), sb = __expf(mc - mm);
            O = O * sa + oc * sb;
            L = L * sa + lc * sb;
            M = mm;
        }
        acc += O / L;
    }
    acc *= (1.0f / NF);
    ms[d] = acc;
    __syncthreads();

    float ov = o_b[d];
    for (int k = 0; k < HIDD; k++) ov += ms[k] * o_w[k * HIDD + d];

    float s1 = ov, s2 = ov * ov;
    #pragma unroll
    for (int m = 32; m >= 1; m >>= 1) { s1 += __shfl_xor(s1, m); s2 += __shfl_xor(s2, m); }
    if ((d & 63) == 0) { w1[d >> 6] = s1; w2[d >> 6] = s2; }
    __syncthreads();
    float S1 = w1[0] + w1[1], S2 = w2[0] + w2[1];
    float mu  = S1 * (1.0f / HIDD);
    float var = S2 * (1.0f / HIDD) - mu * mu;
    float r   = rsqrtf(var + EPSF);
    float lnv = (ov - mu) * r * f_ln_w[d] + f_ln_b[d];
    lnbuf[d] = lnv;
    __syncthreads();

    float fv = f_b[d];
    for (int k = 0; k < HIDD; k++) fv += lnbuf[k] * f_w[k * HIDD + d];
    fv = fv / (1.0f + __expf(-fv));

    out[((size_t)(b * TT + t)) * FDD + d] = fv;
}

// ---------------------------------------------------------------------------
extern "C" void kernel_launch(void* const* d_in, const int* in_sizes, int n_in,
                              void* d_out, int out_size, void* d_ws, size_t ws_size,
                              hipStream_t stream)
{
    const float* x      = (const float*)d_in[0];
    const float* g_ln_w = (const float*)d_in[1];
    const float* g_ln_b = (const float*)d_in[2];
    const float* g_w1   = (const float*)d_in[3];
    const float* g_b1   = (const float*)d_in[4];
    const float* g_w2   = (const float*)d_in[5];
    const float* g_b2   = (const float*)d_in[6];
    const float* q_w    = (const float*)d_in[7];
    const float* q_b    = (const float*)d_in[8];
    const float* k_w    = (const float*)d_in[9];
    const float* k_b    = (const float*)d_in[10];
    const float* v_w    = (const float*)d_in[11];
    const float* v_b    = (const float*)d_in[12];
    const float* o_w    = (const float*)d_in[13];
    const float* o_b    = (const float*)d_in[14];
    const float* f_ln_w = (const float*)d_in[15];
    const float* f_ln_b = (const float*)d_in[16];
    const float* f_w    = (const float*)d_in[17];
    const float* f_b    = (const float*)d_in[18];

    const size_t ntok = (size_t)BB * NHH * LL * HDD;     // 786432 bf16 elems/array
    unsigned short* Qh  = (unsigned short*)d_ws;
    unsigned short* Ql  = Qh  + ntok;
    unsigned short* Kh  = Ql  + ntok;
    unsigned short* Kl  = Kh  + ntok;
    unsigned short* Vth = Kl  + ntok;
    // region [Vth+ntok, Vth+2*ntok) kept reserved (was Vtl) so the P offset
    // and NCH arithmetic stay identical to the proven R9-R12 layout.
    float* Pw = (float*)(Vth + 2 * ntok);                // split-K partials

    const long long bf_floats = (long long)(6 * ntok) / 2;          // 2359296
    const long long unit = 8LL * NQT16 * 16 * 36;                   // 884736 fl/chunk
    long long avail = (long long)(ws_size / 4) - bf_floats - 4096;  // slack
    int NCH = (int)(avail / unit);
    if (NCH > 6) NCH = 6;
    if (NCH < 1) NCH = 1;
    const int C = 64 * ((LL + 64 * NCH - 1) / (64 * NCH));          // keys/chunk

    gate_qkv_kernel<<<(BB * LL) / 4, 128, 0, stream>>>(
        x, g_ln_w, g_ln_b, g_w1, g_b1, g_w2, g_b2,
        q_w, q_b, k_w, k_b, v_w, v_b, Qh, Ql, Kh, Kl, Vth);

    attn_mfma<<<(LL / 64) * NCH * BB * NHH, 256, 0, stream>>>(
        Qh, Ql, Kh, Kl, Vth, Pw, C, NCH);

    final_kernel<<<dim3(TT, BB), 128, 0, stream>>>(
        Pw, o_w, o_b, f_ln_w, f_ln_b, f_w, f_b, (float*)d_out, C, NCH);
}

// Round 15
// 163.548 us; speedup vs baseline: 1.1841x; 1.0170x over previous
//
#include <hip/hip_runtime.h>
#include <hip/hip_bf16.h>

#define BB   2
#define TT   512
#define NF   6
#define DD   32
#define HIDD 128
#define NHH  4
#define HDD  32
#define GHH  32
#define FDD  128
#define LL   (TT*NF)      // 3072
#define EPSF 1e-5f
#define NQT16 (LL/16)     // 192

typedef __attribute__((ext_vector_type(8))) short  bf16x8;
typedef __attribute__((ext_vector_type(4))) float  f32x4;

#define MFMA16x16x32(a,b,c) __builtin_amdgcn_mfma_f32_16x16x32_bf16(a,b,c,0,0,0)

__device__ __forceinline__ unsigned short bfh(float f) {
    union { __hip_bfloat16 b; unsigned short u; } cv;
    cv.b = __float2bfloat16(f);
    return cv.u;
}
__device__ __forceinline__ float bff(unsigned short u) {
    return __uint_as_float(((unsigned)u) << 16);
}
__device__ __forceinline__ unsigned pk_bf16(float a, float b) {
    union { __hip_bfloat162 h2; unsigned u; } cv;
    cv.h2 = __float22bfloat162_rn(make_float2(a, b));
    return cv.u;
}
__device__ __forceinline__ bf16x8 ld8(const unsigned short* p) {
    return *reinterpret_cast<const bf16x8*>(p);
}

// 8 frags per 64-key tile: K hi for 2 permuted frag rows x 2 key halves,
// V hi for 2 dim halves x 2 key halves. K-lo split dropped this round
// (Q stays hi/lo): S=(qh+ql)*kh — K's 2^-9 relative error adds ~0.002|S|
// to scores; R13 showed P-quantization dominates absmax, so this is in
// budget. V-lo was dropped in R13 (observed free).
struct Frags {
    bf16x8 k0, k1;   // keys X = [j0, j0+32), frag rows 0/1
    bf16x8 k2, k3;   // keys Y = [j0+32, j0+64)
    bf16x8 v0, v1, v2, v3;   // V^T hi: (dims rr / rr+16) x (X / Y)
};

__device__ __forceinline__ void load_tile(
    const unsigned short* __restrict__ Kh,
    const unsigned short* __restrict__ Vth,
    size_t hbT, int j0, int kloc0, int kloc1, int quad,
    size_t vb0, size_t vb1, Frags& f)
{
    const size_t kX0 = (hbT + j0 + kloc0) * HDD + quad * 8;
    const size_t kX1 = (hbT + j0 + kloc1) * HDD + quad * 8;
    f.k0 = ld8(Kh + kX0);
    f.k1 = ld8(Kh + kX1);
    f.k2 = ld8(Kh + kX0 + (size_t)32 * HDD);
    f.k3 = ld8(Kh + kX1 + (size_t)32 * HDD);
    const size_t vX = (size_t)j0 + quad * 8, vY = vX + 32;
    f.v0 = ld8(Vth + vb0 + vX);
    f.v1 = ld8(Vth + vb1 + vX);
    f.v2 = ld8(Vth + vb0 + vY);
    f.v3 = ld8(Vth + vb1 + vY);
}

// One tile's scores + online softmax + PV, updating (m, l, o0, o1).
// Local key of score element r: s0=8q+r, s1=8q+4+r, s2=32+8q+r, s3=36+8q+r.
__device__ __forceinline__ void compute_tile(
    const Frags& f, const bf16x8 qfh, const bf16x8 qfl,
    int j0, int jminw, int jend, int quad,
    float& m, float& l, f32x4& o0, f32x4& o1)
{
    const f32x4 z = {0.f, 0.f, 0.f, 0.f};
    f32x4 s0 = MFMA16x16x32(f.k0, qfh, z);
    f32x4 s1 = MFMA16x16x32(f.k1, qfh, z);
    f32x4 s2 = MFMA16x16x32(f.k2, qfh, z);
    f32x4 s3 = MFMA16x16x32(f.k3, qfh, z);
    s0 = MFMA16x16x32(f.k0, qfl, s0);
    s1 = MFMA16x16x32(f.k1, qfl, s1);
    s2 = MFMA16x16x32(f.k2, qfl, s2);
    s3 = MFMA16x16x32(f.k3, qfl, s3);

    float e[16], mx, ls, corr;
    if (j0 + 64 <= jminw) {
        // interior tile: all keys live for every row in the wave
        f32x4 m4 = s0;
        #pragma unroll
        for (int r2 = 0; r2 < 4; r2++)
            m4[r2] = fmaxf(fmaxf(m4[r2], s1[r2]), fmaxf(s2[r2], s3[r2]));
        mx = fmaxf(fmaxf(m4[0], m4[1]), fmaxf(m4[2], m4[3]));
        mx = fmaxf(mx, __shfl_xor(mx, 16));
        mx = fmaxf(mx, __shfl_xor(mx, 32));
        mx = fmaxf(m, mx);
        corr = __expf(m - mx); m = mx;
        ls = 0.f;
        #pragma unroll
        for (int r2 = 0; r2 < 4; r2++) {
            float e0 = __expf(s0[r2] - mx);
            float e1 = __expf(s1[r2] - mx);
            float e2 = __expf(s2[r2] - mx);
            float e3 = __expf(s3[r2] - mx);
            e[r2] = e0; e[4 + r2] = e1; e[8 + r2] = e2; e[12 + r2] = e3;
            ls += (e0 + e1) + (e2 + e3);
        }
    } else {
        // boundary tile: per-key prefix masking (mask pre-max, zero exp)
        const int je = jend - j0;
        const int k0 = 8 * quad;
        float t[16];
        #pragma unroll
        for (int r2 = 0; r2 < 4; r2++) {
            t[r2]      = (k0 + r2          < je) ? s0[r2] : -1e30f;
            t[4 + r2]  = (k0 + 4 + r2      < je) ? s1[r2] : -1e30f;
            t[8 + r2]  = (32 + k0 + r2     < je) ? s2[r2] : -1e30f;
            t[12 + r2] = (32 + k0 + 4 + r2 < je) ? s3[r2] : -1e30f;
        }
        mx = t[0];
        #pragma unroll
        for (int i = 1; i < 16; i++) mx = fmaxf(mx, t[i]);
        mx = fmaxf(mx, __shfl_xor(mx, 16));
        mx = fmaxf(mx, __shfl_xor(mx, 32));
        mx = fmaxf(m, mx);
        corr = __expf(m - mx); m = mx;
        ls = 0.f;
        #pragma unroll
        for (int r2 = 0; r2 < 4; r2++) {
            float e0 = __expf(t[r2] - mx);
            float e1 = __expf(t[4 + r2] - mx);
            float e2 = __expf(t[8 + r2] - mx);
            float e3 = __expf(t[12 + r2] - mx);
            e0 = (k0 + r2          < je) ? e0 : 0.f;   // kill exp(0)=1
            e1 = (k0 + 4 + r2      < je) ? e1 : 0.f;
            e2 = (32 + k0 + r2     < je) ? e2 : 0.f;
            e3 = (32 + k0 + 4 + r2 < je) ? e3 : 0.f;
            e[r2] = e0; e[4 + r2] = e1; e[8 + r2] = e2; e[12 + r2] = e3;
            ls += (e0 + e1) + (e2 + e3);
        }
    }
    l = l * corr + ls;
    #pragma unroll
    for (int i = 0; i < 4; i++) { o0[i] *= corr; o1[i] *= corr; }

    union { unsigned u[4]; bf16x8 v; } pbX, pbY;
    pbX.u[0] = pk_bf16(e[0],  e[1]);
    pbX.u[1] = pk_bf16(e[2],  e[3]);
    pbX.u[2] = pk_bf16(e[4],  e[5]);
    pbX.u[3] = pk_bf16(e[6],  e[7]);
    pbY.u[0] = pk_bf16(e[8],  e[9]);
    pbY.u[1] = pk_bf16(e[10], e[11]);
    pbY.u[2] = pk_bf16(e[12], e[13]);
    pbY.u[3] = pk_bf16(e[14], e[15]);

    o0 = MFMA16x16x32(f.v0, pbX.v, o0);
    o1 = MFMA16x16x32(f.v1, pbX.v, o1);
    o0 = MFMA16x16x32(f.v2, pbY.v, o0);
    o1 = MFMA16x16x32(f.v3, pbY.v, o1);
}

// ---------------------------------------------------------------------------
// Kernel 1: gater + gated QKV. 4 tokens per block, 128 threads (2 waves),
// one output column per thread. Emits Qh/Ql (hi/lo split, pre-scaled by
// 1/sqrt(32)), Kh (bf16 round-to-nearest — lo split dropped), token-major
// [bh][tok][32]; V hi TRANSPOSED [bh][dim][tok].
// ---------------------------------------------------------------------------
__global__ __launch_bounds__(128) void gate_qkv_kernel(
    const float* __restrict__ x,
    const float* __restrict__ g_ln_w, const float* __restrict__ g_ln_b,
    const float* __restrict__ g_w1,   const float* __restrict__ g_b1,
    const float* __restrict__ g_w2,   const float* __restrict__ g_b2,
    const float* __restrict__ q_w,    const float* __restrict__ q_b,
    const float* __restrict__ k_w,    const float* __restrict__ k_b,
    const float* __restrict__ v_w,    const float* __restrict__ v_b,
    unsigned short* __restrict__ Qh, unsigned short* __restrict__ Ql,
    unsigned short* __restrict__ Kh,
    unsigned short* __restrict__ Vth)
{
    const int tok0 = blockIdx.x * 4;
    const int tid  = threadIdx.x;

    __shared__ float xs[4][DD];
    __shared__ float lns[4][DD];
    __shared__ float hs[4][GHH];
    __shared__ float gate_s[4];

    xs[tid >> 5][tid & 31] = x[(size_t)tok0 * DD + tid];
    __syncthreads();

    const int tk = (tid >> 5) & 1;
    const int d5 = tid & 31;
    if (tid < 64) {
        #pragma unroll
        for (int tt = 0; tt < 2; tt++) {
            int t = tt * 2 + tk;
            float xv = xs[t][d5];
            float s1 = xv, s2 = xv * xv;
            #pragma unroll
            for (int m = 16; m >= 1; m >>= 1) {
                s1 += __shfl_xor(s1, m, 32);
                s2 += __shfl_xor(s2, m, 32);
            }
            float mu  = s1 * (1.0f / DD);
            float var = s2 * (1.0f / DD) - mu * mu;
            float r   = rsqrtf(var + EPSF);
            lns[t][d5] = (xv - mu) * r * g_ln_w[d5] + g_ln_b[d5];
        }
    }
    __syncthreads();
    if (tid < 64) {
        #pragma unroll
        for (int tt = 0; tt < 2; tt++) {
            int t = tt * 2 + tk;
            float acc = g_b1[d5];
            #pragma unroll
            for (int d = 0; d < DD; d++) acc += lns[t][d] * g_w1[d * GHH + d5];
            hs[t][d5] = acc / (1.0f + __expf(-acc));
        }
    }
    __syncthreads();
    if (tid < 64) {
        #pragma unroll
        for (int tt = 0; tt < 2; tt++) {
            int t = tt * 2 + tk;
            float p = hs[t][d5] * g_w2[d5];
            #pragma unroll
            for (int m = 16; m >= 1; m >>= 1) p += __shfl_xor(p, m, 32);
            if (d5 == 0) gate_s[t] = 1.0f / (1.0f + __expf(-(p + g_b2[0])));
        }
    }
    __syncthreads();

    const int col = tid;
    float aq[4], ak[4], av[4];
    #pragma unroll
    for (int t = 0; t < 4; t++) { aq[t] = q_b[col]; ak[t] = k_b[col]; av[t] = v_b[col]; }
    #pragma unroll
    for (int d = 0; d < DD; d++) {
        float wq = q_w[d * HIDD + col];
        float wk = k_w[d * HIDD + col];
        float wv = v_w[d * HIDD + col];
        #pragma unroll
        for (int t = 0; t < 4; t++) {
            float xd = xs[t][d];
            aq[t] += xd * wq; ak[t] += xd * wk; av[t] += xd * wv;
        }
    }

    const int b    = tok0 / LL;
    const int l0   = tok0 - b * LL;
    const int head = col >> 5;
    const int d5c  = col & 31;
    const float scale = 0.17677669529663688f;   // 1/sqrt(32), folded into Q

    unsigned short vh[4];
    #pragma unroll
    for (int t = 0; t < 4; t++) {
        const float g = gate_s[t];
        const size_t a = ((size_t)(b * NHH + head) * LL + l0 + t) * HDD + d5c;
        float qv = aq[t] * g * scale;
        unsigned short h = bfh(qv); Qh[a] = h; Ql[a] = bfh(qv - bff(h));
        Kh[a] = bfh(ak[t] * g);
        vh[t] = bfh(av[t] * g);
    }
    const size_t vbase = ((size_t)(b * NHH + head) * HDD + d5c) * LL + l0;
    *(ushort4*)(Vth + vbase) = make_ushort4(vh[0], vh[1], vh[2], vh[3]);
}

// ---------------------------------------------------------------------------
// Kernel 2: MFMA flash-attention partials — DUAL-STREAM ILP (R13-proven):
// two tiles per loop iteration with independent online-softmax states,
// merged at the end (flash-decoding). Both tiles' 16 loads issue before
// either stream's first waitcnt — compiler-proof latency overlap.
// K-lo dropped: 8 loads + 12 MFMAs per tile (was 12/16).
// Grid 1-D, bh = blockIdx.x & 7 (XCD-local K/V — R11 verified).
// ---------------------------------------------------------------------------
__global__ __launch_bounds__(256) void attn_mfma(
    const unsigned short* __restrict__ Qh, const unsigned short* __restrict__ Ql,
    const unsigned short* __restrict__ Kh,
    const unsigned short* __restrict__ Vth,
    float* __restrict__ P, int C, int NCH)
{
    const int lin = blockIdx.x;
    const int bh  = lin & 7;                    // XCD-local clustering
    const int jj  = lin >> 3;
    const int ch  = jj / (LL / 64);
    const int qt  = (LL / 64 - 1) - (jj % (LL / 64));   // heavy prefixes first
    const int j0c = C * ch;
    const int jmax_blk = ((qt * 64 + 63) / NF + 1) * NF;
    if (j0c >= jmax_blk) return;           // dead chunk, uniform exit

    const int tid  = threadIdx.x;
    const int w    = tid >> 6;
    const int lane = tid & 63;
    const int rr   = lane & 15;            // query row in 16 / V-dim / B n-index
    const int quad = lane >> 4;

    const int ig0   = qt * 64 + w * 16;
    const int ig    = ig0 + rr;
    const int jend  = (ig / NF + 1) * NF;
    const int jmaxw = ((ig0 + 15) / NF + 1) * NF;
    const int jminw = (ig0 / NF + 1) * NF;

    const int kend = min(jmaxw - j0c, C);
    if (kend <= 0) return;                 // dead wave (partial never read)

    const size_t hbT = (size_t)bh * LL;
    const size_t qo  = (hbT + ig) * HDD + quad * 8;
    const bf16x8 qfh = ld8(Qh + qo);
    const bf16x8 qfl = ld8(Ql + qo);

    // permuted local key for A-frag row m=rr: frag f -> key 8*(m>>2)+4f+(m&3)
    const int kloc0 = 8 * (rr >> 2) + (rr & 3);
    const int kloc1 = kloc0 + 4;

    const size_t vb0 = ((size_t)bh * HDD + rr)      * LL;
    const size_t vb1 = ((size_t)bh * HDD + rr + 16) * LL;

    f32x4 oA0 = {0.f,0.f,0.f,0.f}, oA1 = {0.f,0.f,0.f,0.f};
    f32x4 oB0 = {0.f,0.f,0.f,0.f}, oB1 = {0.f,0.f,0.f,0.f};
    float mA = -1e30f, lA = 0.f, mB = -1e30f, lB = 0.f;

    // 64-key tiles; C and LL are multiples of 64, so over-reads (incl. the
    // clamped duplicate B-load on an odd tail) stay inside [0, LL).
    const int ntile = (kend + 63) >> 6;

    for (int i = 0; i < ntile; i += 2) {
        const int  j0A  = j0c + (i << 6);
        const bool hasB = (i + 1 < ntile);
        const int  j0B  = j0c + ((hasB ? i + 1 : i) << 6);  // clamp: load-only dup

        Frags fA, fB;
        load_tile(Kh, Vth, hbT, j0A, kloc0, kloc1, quad, vb0, vb1, fA);
        load_tile(Kh, Vth, hbT, j0B, kloc0, kloc1, quad, vb0, vb1, fB);

        compute_tile(fA, qfh, qfl, j0A, jminw, jend, quad, mA, lA, oA0, oA1);
        if (hasB)
            compute_tile(fB, qfh, qfl, j0B, jminw, jend, quad, mB, lB, oB0, oB1);
    }

    // merge the two streams (flash-decoding): per-lane, same quad structure.
    // If stream B never ran, mB=-1e30 -> wb=0 and it contributes nothing.
    const float mm = fmaxf(mA, mB);
    const float wa = __expf(mA - mm), wb = __expf(mB - mm);
    float l = lA * wa + lB * wb;
    f32x4 o0, o1;
    #pragma unroll
    for (int i = 0; i < 4; i++) {
        o0[i] = oA0[i] * wa + oB0[i] * wb;
        o1[i] = oA1[i] * wa + oB1[i] * wb;
    }

    // l holds only this lane's per-tile partials; quads share the same m
    // scale, so the row denominator is the cross-quad sum (R8 bug fix).
    l += __shfl_xor(l, 16);
    l += __shfl_xor(l, 32);

    // write chunk partial: P[bh][qt16][ch][row16][36]
    float* dst = P + ((((size_t)bh * NQT16 + (ig0 >> 4)) * NCH + ch) * 16 + rr) * 36;
    *(f32x4*)(dst + quad * 4)      = o0;   // dims quad*4 .. +3
    *(f32x4*)(dst + 16 + quad * 4) = o1;   // dims 16+quad*4 .. +3
    if (quad == 0) { dst[32] = mm; dst[33] = l; }
}

// ---------------------------------------------------------------------------
// Kernel 3: chunk-merge (flash-decoding) + mean-pool + o-proj + LN + f-proj
// + SiLU. Block per (t, b), 128 threads. (unchanged — proven)
// ---------------------------------------------------------------------------
__global__ __launch_bounds__(128) void final_kernel(
    const float* __restrict__ P,
    const float* __restrict__ o_w,    const float* __restrict__ o_b,
    const float* __restrict__ f_ln_w, const float* __restrict__ f_ln_b,
    const float* __restrict__ f_w,    const float* __restrict__ f_b,
    float* __restrict__ out, int C, int NCH)
{
    const int t = blockIdx.x;
    const int b = blockIdx.y;
    const int d = threadIdx.x;     // 0..127
    const int h  = d >> 5;         // head
    const int hd = d & 31;         // dim within head
    const int bh = b * NHH + h;

    __shared__ float ms[HIDD];
    __shared__ float lnbuf[HIDD];
    __shared__ float w1[2], w2[2];

    const int jmax = (t + 1) * NF;
    const int nch  = min(NCH, (jmax + C - 1) / C);

    float acc = 0.0f;
    #pragma unroll
    for (int f = 0; f < NF; f++) {
        const int row = t * NF + f;
        const int qt16 = row >> 4;
        const int r    = row & 15;
        float M = -1e30f, L = 0.0f, O = 0.0f;
        for (int c = 0; c < nch; c++) {
            const float* pr = P + ((((size_t)bh * NQT16 + qt16) * NCH + c) * 16 + r) * 36;
            const float mc = pr[32], lc = pr[33], oc = pr[hd];
            const float mm = fmaxf(M, mc);
            const float sa = __expf(M - mm), sb = __expf(mc - mm);
            O = O * sa + oc * sb;
            L = L * sa + lc * sb;
            M = mm;
        }
        acc += O / L;
    }
    acc *= (1.0f / NF);
    ms[d] = acc;
    __syncthreads();

    float ov = o_b[d];
    for (int k = 0; k < HIDD; k++) ov += ms[k] * o_w[k * HIDD + d];

    float s1 = ov, s2 = ov * ov;
    #pragma unroll
    for (int m = 32; m >= 1; m >>= 1) { s1 += __shfl_xor(s1, m); s2 += __shfl_xor(s2, m); }
    if ((d & 63) == 0) { w1[d >> 6] = s1; w2[d >> 6] = s2; }
    __syncthreads();
    float S1 = w1[0] + w1[1], S2 = w2[0] + w2[1];
    float mu  = S1 * (1.0f / HIDD);
    float var = S2 * (1.0f / HIDD) - mu * mu;
    float r   = rsqrtf(var + EPSF);
    float lnv = (ov - mu) * r * f_ln_w[d] + f_ln_b[d];
    lnbuf[d] = lnv;
    __syncthreads();

    float fv = f_b[d];
    for (int k = 0; k < HIDD; k++) fv += lnbuf[k] * f_w[k * HIDD + d];
    fv = fv / (1.0f + __expf(-fv));

    out[((size_t)(b * TT + t)) * FDD + d] = fv;
}

// ---------------------------------------------------------------------------
extern "C" void kernel_launch(void* const* d_in, const int* in_sizes, int n_in,
                              void* d_out, int out_size, void* d_ws, size_t ws_size,
                              hipStream_t stream)
{
    const float* x      = (const float*)d_in[0];
    const float* g_ln_w = (const float*)d_in[1];
    const float* g_ln_b = (const float*)d_in[2];
    const float* g_w1   = (const float*)d_in[3];
    const float* g_b1   = (const float*)d_in[4];
    const float* g_w2   = (const float*)d_in[5];
    const float* g_b2   = (const float*)d_in[6];
    const float* q_w    = (const float*)d_in[7];
    const float* q_b    = (const float*)d_in[8];
    const float* k_w    = (const float*)d_in[9];
    const float* k_b    = (const float*)d_in[10];
    const float* v_w    = (const float*)d_in[11];
    const float* v_b    = (const float*)d_in[12];
    const float* o_w    = (const float*)d_in[13];
    const float* o_b    = (const float*)d_in[14];
    const float* f_ln_w = (const float*)d_in[15];
    const float* f_ln_b = (const float*)d_in[16];
    const float* f_w    = (const float*)d_in[17];
    const float* f_b    = (const float*)d_in[18];

    const size_t ntok = (size_t)BB * NHH * LL * HDD;     // 786432 bf16 elems/array
    unsigned short* Qh  = (unsigned short*)d_ws;
    unsigned short* Ql  = Qh  + ntok;
    unsigned short* Kh  = Ql  + ntok;
    // region [Kh+ntok, Kh+2*ntok) reserved (was Kl) — layout kept identical
    unsigned short* Vth = Kh + 2 * ntok;
    // region [Vth+ntok, Vth+2*ntok) reserved (was Vtl)
    float* Pw = (float*)(Vth + 2 * ntok);                // split-K partials

    const long long bf_floats = (long long)(6 * ntok) / 2;          // 2359296
    const long long unit = 8LL * NQT16 * 16 * 36;                   // 884736 fl/chunk
    long long avail = (long long)(ws_size / 4) - bf_floats - 4096;  // slack
    int NCH = (int)(avail / unit);
    if (NCH > 8) NCH = 8;
    if (NCH < 1) NCH = 1;
    const int C = 64 * ((LL + 64 * NCH - 1) / (64 * NCH));          // keys/chunk

    gate_qkv_kernel<<<(BB * LL) / 4, 128, 0, stream>>>(
        x, g_ln_w, g_ln_b, g_w1, g_b1, g_w2, g_b2,
        q_w, q_b, k_w, k_b, v_w, v_b, Qh, Ql, Kh, Vth);

    attn_mfma<<<(LL / 64) * NCH * BB * NHH, 256, 0, stream>>>(
        Qh, Ql, Kh, Vth, Pw, C, NCH);

    final_kernel<<<dim3(TT, BB), 128, 0, stream>>>(
        Pw, o_w, o_b, f_ln_w, f_ln_b, f_w, f_b, (float*)d_out, C, NCH);
}

// Round 16
// 153.046 us; speedup vs baseline: 1.2654x; 1.0686x over previous
//
#include <hip/hip_runtime.h>
#include <hip/hip_bf16.h>

#define BB   2
#define TT   512
#define NF   6
#define DD   32
#define HIDD 128
#define NHH  4
#define HDD  32
#define GHH  32
#define FDD  128
#define LL   (TT*NF)      // 3072
#define EPSF 1e-5f
#define NQT16 (LL/16)     // 192

typedef __attribute__((ext_vector_type(8))) short  bf16x8;
typedef __attribute__((ext_vector_type(4))) float  f32x4;

#define MFMA16x16x32(a,b,c) __builtin_amdgcn_mfma_f32_16x16x32_bf16(a,b,c,0,0,0)

__device__ __forceinline__ unsigned short bfh(float f) {
    union { __hip_bfloat16 b; unsigned short u; } cv;
    cv.b = __float2bfloat16(f);
    return cv.u;
}
__device__ __forceinline__ float bff(unsigned short u) {
    return __uint_as_float(((unsigned)u) << 16);
}
__device__ __forceinline__ unsigned pk_bf16(float a, float b) {
    union { __hip_bfloat162 h2; unsigned u; } cv;
    cv.h2 = __float22bfloat162_rn(make_float2(a, b));
    return cv.u;
}
__device__ __forceinline__ bf16x8 ld8(const unsigned short* p) {
    return *reinterpret_cast<const bf16x8*>(p);
}

// 8 frags per 64-key tile: K hi for 2 permuted frag rows x 2 key halves,
// V hi for 2 dim halves x 2 key halves (K-lo and V-lo splits dropped —
// R13/R14 verified absmax unchanged at 0.0078).
struct Frags {
    bf16x8 k0, k1;   // keys X = [j0, j0+32), frag rows 0/1
    bf16x8 k2, k3;   // keys Y = [j0+32, j0+64)
    bf16x8 v0, v1, v2, v3;   // V^T hi: (dims rr / rr+16) x (X / Y)
};

__device__ __forceinline__ void load_tile(
    const unsigned short* __restrict__ Kh,
    const unsigned short* __restrict__ Vth,
    size_t hbT, int j0, int kloc0, int kloc1, int quad,
    size_t vb0, size_t vb1, Frags& f)
{
    const size_t kX0 = (hbT + j0 + kloc0) * HDD + quad * 8;
    const size_t kX1 = (hbT + j0 + kloc1) * HDD + quad * 8;
    f.k0 = ld8(Kh + kX0);
    f.k1 = ld8(Kh + kX1);
    f.k2 = ld8(Kh + kX0 + (size_t)32 * HDD);
    f.k3 = ld8(Kh + kX1 + (size_t)32 * HDD);
    const size_t vX = (size_t)j0 + quad * 8, vY = vX + 32;
    f.v0 = ld8(Vth + vb0 + vX);
    f.v1 = ld8(Vth + vb1 + vX);
    f.v2 = ld8(Vth + vb0 + vY);
    f.v3 = ld8(Vth + vb1 + vY);
}

// One tile's scores + online softmax + PV, updating (m, l, o0, o1).
// Local key of score element r: s0=8q+r, s1=8q+4+r, s2=32+8q+r, s3=36+8q+r.
__device__ __forceinline__ void compute_tile(
    const Frags& f, const bf16x8 qfh, const bf16x8 qfl,
    int j0, int jminw, int jend, int quad,
    float& m, float& l, f32x4& o0, f32x4& o1)
{
    const f32x4 z = {0.f, 0.f, 0.f, 0.f};
    f32x4 s0 = MFMA16x16x32(f.k0, qfh, z);
    f32x4 s1 = MFMA16x16x32(f.k1, qfh, z);
    f32x4 s2 = MFMA16x16x32(f.k2, qfh, z);
    f32x4 s3 = MFMA16x16x32(f.k3, qfh, z);
    s0 = MFMA16x16x32(f.k0, qfl, s0);
    s1 = MFMA16x16x32(f.k1, qfl, s1);
    s2 = MFMA16x16x32(f.k2, qfl, s2);
    s3 = MFMA16x16x32(f.k3, qfl, s3);

    float e[16], mx, ls, corr;
    if (j0 + 64 <= jminw) {
        // interior tile: all keys live for every row in the wave
        f32x4 m4 = s0;
        #pragma unroll
        for (int r2 = 0; r2 < 4; r2++)
            m4[r2] = fmaxf(fmaxf(m4[r2], s1[r2]), fmaxf(s2[r2], s3[r2]));
        mx = fmaxf(fmaxf(m4[0], m4[1]), fmaxf(m4[2], m4[3]));
        mx = fmaxf(mx, __shfl_xor(mx, 16));
        mx = fmaxf(mx, __shfl_xor(mx, 32));
        mx = fmaxf(m, mx);
        corr = __expf(m - mx); m = mx;
        ls = 0.f;
        #pragma unroll
        for (int r2 = 0; r2 < 4; r2++) {
            float e0 = __expf(s0[r2] - mx);
            float e1 = __expf(s1[r2] - mx);
            float e2 = __expf(s2[r2] - mx);
            float e3 = __expf(s3[r2] - mx);
            e[r2] = e0; e[4 + r2] = e1; e[8 + r2] = e2; e[12 + r2] = e3;
            ls += (e0 + e1) + (e2 + e3);
        }
    } else {
        // boundary tile: per-key prefix masking (mask pre-max, zero exp)
        const int je = jend - j0;
        const int k0 = 8 * quad;
        float t[16];
        #pragma unroll
        for (int r2 = 0; r2 < 4; r2++) {
            t[r2]      = (k0 + r2          < je) ? s0[r2] : -1e30f;
            t[4 + r2]  = (k0 + 4 + r2      < je) ? s1[r2] : -1e30f;
            t[8 + r2]  = (32 + k0 + r2     < je) ? s2[r2] : -1e30f;
            t[12 + r2] = (32 + k0 + 4 + r2 < je) ? s3[r2] : -1e30f;
        }
        mx = t[0];
        #pragma unroll
        for (int i = 1; i < 16; i++) mx = fmaxf(mx, t[i]);
        mx = fmaxf(mx, __shfl_xor(mx, 16));
        mx = fmaxf(mx, __shfl_xor(mx, 32));
        mx = fmaxf(m, mx);
        corr = __expf(m - mx); m = mx;
        ls = 0.f;
        #pragma unroll
        for (int r2 = 0; r2 < 4; r2++) {
            float e0 = __expf(t[r2] - mx);
            float e1 = __expf(t[4 + r2] - mx);
            float e2 = __expf(t[8 + r2] - mx);
            float e3 = __expf(t[12 + r2] - mx);
            e0 = (k0 + r2          < je) ? e0 : 0.f;   // kill exp(0)=1
            e1 = (k0 + 4 + r2      < je) ? e1 : 0.f;
            e2 = (32 + k0 + r2     < je) ? e2 : 0.f;
            e3 = (32 + k0 + 4 + r2 < je) ? e3 : 0.f;
            e[r2] = e0; e[4 + r2] = e1; e[8 + r2] = e2; e[12 + r2] = e3;
            ls += (e0 + e1) + (e2 + e3);
        }
    }
    l = l * corr + ls;
    #pragma unroll
    for (int i = 0; i < 4; i++) { o0[i] *= corr; o1[i] *= corr; }

    union { unsigned u[4]; bf16x8 v; } pbX, pbY;
    pbX.u[0] = pk_bf16(e[0],  e[1]);
    pbX.u[1] = pk_bf16(e[2],  e[3]);
    pbX.u[2] = pk_bf16(e[4],  e[5]);
    pbX.u[3] = pk_bf16(e[6],  e[7]);
    pbY.u[0] = pk_bf16(e[8],  e[9]);
    pbY.u[1] = pk_bf16(e[10], e[11]);
    pbY.u[2] = pk_bf16(e[12], e[13]);
    pbY.u[3] = pk_bf16(e[14], e[15]);

    o0 = MFMA16x16x32(f.v0, pbX.v, o0);
    o1 = MFMA16x16x32(f.v1, pbX.v, o1);
    o0 = MFMA16x16x32(f.v2, pbY.v, o0);
    o1 = MFMA16x16x32(f.v3, pbY.v, o1);
}

// ---------------------------------------------------------------------------
// Kernel 1: gater + gated QKV. 4 tokens per block, 128 threads (2 waves),
// one output column per thread. Emits Qh/Ql (hi/lo split, pre-scaled by
// 1/sqrt(32)), Kh (bf16 rtn), token-major [bh][tok][32]; V hi TRANSPOSED
// [bh][dim][tok]. (unchanged from R14 — proven)
// ---------------------------------------------------------------------------
__global__ __launch_bounds__(128) void gate_qkv_kernel(
    const float* __restrict__ x,
    const float* __restrict__ g_ln_w, const float* __restrict__ g_ln_b,
    const float* __restrict__ g_w1,   const float* __restrict__ g_b1,
    const float* __restrict__ g_w2,   const float* __restrict__ g_b2,
    const float* __restrict__ q_w,    const float* __restrict__ q_b,
    const float* __restrict__ k_w,    const float* __restrict__ k_b,
    const float* __restrict__ v_w,    const float* __restrict__ v_b,
    unsigned short* __restrict__ Qh, unsigned short* __restrict__ Ql,
    unsigned short* __restrict__ Kh,
    unsigned short* __restrict__ Vth)
{
    const int tok0 = blockIdx.x * 4;
    const int tid  = threadIdx.x;

    __shared__ float xs[4][DD];
    __shared__ float lns[4][DD];
    __shared__ float hs[4][GHH];
    __shared__ float gate_s[4];

    xs[tid >> 5][tid & 31] = x[(size_t)tok0 * DD + tid];
    __syncthreads();

    const int tk = (tid >> 5) & 1;
    const int d5 = tid & 31;
    if (tid < 64) {
        #pragma unroll
        for (int tt = 0; tt < 2; tt++) {
            int t = tt * 2 + tk;
            float xv = xs[t][d5];
            float s1 = xv, s2 = xv * xv;
            #pragma unroll
            for (int m = 16; m >= 1; m >>= 1) {
                s1 += __shfl_xor(s1, m, 32);
                s2 += __shfl_xor(s2, m, 32);
            }
            float mu  = s1 * (1.0f / DD);
            float var = s2 * (1.0f / DD) - mu * mu;
            float r   = rsqrtf(var + EPSF);
            lns[t][d5] = (xv - mu) * r * g_ln_w[d5] + g_ln_b[d5];
        }
    }
    __syncthreads();
    if (tid < 64) {
        #pragma unroll
        for (int tt = 0; tt < 2; tt++) {
            int t = tt * 2 + tk;
            float acc = g_b1[d5];
            #pragma unroll
            for (int d = 0; d < DD; d++) acc += lns[t][d] * g_w1[d * GHH + d5];
            hs[t][d5] = acc / (1.0f + __expf(-acc));
        }
    }
    __syncthreads();
    if (tid < 64) {
        #pragma unroll
        for (int tt = 0; tt < 2; tt++) {
            int t = tt * 2 + tk;
            float p = hs[t][d5] * g_w2[d5];
            #pragma unroll
            for (int m = 16; m >= 1; m >>= 1) p += __shfl_xor(p, m, 32);
            if (d5 == 0) gate_s[t] = 1.0f / (1.0f + __expf(-(p + g_b2[0])));
        }
    }
    __syncthreads();

    const int col = tid;
    float aq[4], ak[4], av[4];
    #pragma unroll
    for (int t = 0; t < 4; t++) { aq[t] = q_b[col]; ak[t] = k_b[col]; av[t] = v_b[col]; }
    #pragma unroll
    for (int d = 0; d < DD; d++) {
        float wq = q_w[d * HIDD + col];
        float wk = k_w[d * HIDD + col];
        float wv = v_w[d * HIDD + col];
        #pragma unroll
        for (int t = 0; t < 4; t++) {
            float xd = xs[t][d];
            aq[t] += xd * wq; ak[t] += xd * wk; av[t] += xd * wv;
        }
    }

    const int b    = tok0 / LL;
    const int l0   = tok0 - b * LL;
    const int head = col >> 5;
    const int d5c  = col & 31;
    const float scale = 0.17677669529663688f;   // 1/sqrt(32), folded into Q

    unsigned short vh[4];
    #pragma unroll
    for (int t = 0; t < 4; t++) {
        const float g = gate_s[t];
        const size_t a = ((size_t)(b * NHH + head) * LL + l0 + t) * HDD + d5c;
        float qv = aq[t] * g * scale;
        unsigned short h = bfh(qv); Qh[a] = h; Ql[a] = bfh(qv - bff(h));
        Kh[a] = bfh(ak[t] * g);
        vh[t] = bfh(av[t] * g);
    }
    const size_t vbase = ((size_t)(b * NHH + head) * HDD + d5c) * LL + l0;
    *(ushort4*)(Vth + vbase) = make_ushort4(vh[0], vh[1], vh[2], vh[3]);
}

// ---------------------------------------------------------------------------
// Kernel 2: MFMA flash-attention partials — TRIPLE-STREAM ILP (extends the
// R13-proven dual-stream structure): three tiles per loop iteration with
// independent online-softmax states, merged at the end (flash-decoding).
// All 24 loads issue before any stream's first waitcnt — compiler-proof
// latency overlap (R13 tell: VGPR grows, streams stay live). With C=384
// (ntile<=6) the whole chunk runs in 2 loop iterations.
// Grid 1-D, bh = blockIdx.x & 7 (XCD-local K/V — R11 verified).
// ---------------------------------------------------------------------------
__global__ __launch_bounds__(256) void attn_mfma(
    const unsigned short* __restrict__ Qh, const unsigned short* __restrict__ Ql,
    const unsigned short* __restrict__ Kh,
    const unsigned short* __restrict__ Vth,
    float* __restrict__ P, int C, int NCH)
{
    const int lin = blockIdx.x;
    const int bh  = lin & 7;                    // XCD-local clustering
    const int jj  = lin >> 3;
    const int ch  = jj / (LL / 64);
    const int qt  = (LL / 64 - 1) - (jj % (LL / 64));   // heavy prefixes first
    const int j0c = C * ch;
    const int jmax_blk = ((qt * 64 + 63) / NF + 1) * NF;
    if (j0c >= jmax_blk) return;           // dead chunk, uniform exit

    const int tid  = threadIdx.x;
    const int w    = tid >> 6;
    const int lane = tid & 63;
    const int rr   = lane & 15;            // query row in 16 / V-dim / B n-index
    const int quad = lane >> 4;

    const int ig0   = qt * 64 + w * 16;
    const int ig    = ig0 + rr;
    const int jend  = (ig / NF + 1) * NF;
    const int jmaxw = ((ig0 + 15) / NF + 1) * NF;
    const int jminw = (ig0 / NF + 1) * NF;

    const int kend = min(jmaxw - j0c, C);
    if (kend <= 0) return;                 // dead wave (partial never read)

    const size_t hbT = (size_t)bh * LL;
    const size_t qo  = (hbT + ig) * HDD + quad * 8;
    const bf16x8 qfh = ld8(Qh + qo);
    const bf16x8 qfl = ld8(Ql + qo);

    // permuted local key for A-frag row m=rr: frag f -> key 8*(m>>2)+4f+(m&3)
    const int kloc0 = 8 * (rr >> 2) + (rr & 3);
    const int kloc1 = kloc0 + 4;

    const size_t vb0 = ((size_t)bh * HDD + rr)      * LL;
    const size_t vb1 = ((size_t)bh * HDD + rr + 16) * LL;

    f32x4 oA0 = {0.f,0.f,0.f,0.f}, oA1 = {0.f,0.f,0.f,0.f};
    f32x4 oB0 = {0.f,0.f,0.f,0.f}, oB1 = {0.f,0.f,0.f,0.f};
    f32x4 oC0 = {0.f,0.f,0.f,0.f}, oC1 = {0.f,0.f,0.f,0.f};
    float mA = -1e30f, lA = 0.f, mB = -1e30f, lB = 0.f, mC = -1e30f, lC = 0.f;

    // 64-key tiles; C and LL are multiples of 64, so over-reads (incl. the
    // clamped duplicate loads on short tails) stay inside [0, LL).
    const int ntile = (kend + 63) >> 6;

    for (int i = 0; i < ntile; i += 3) {
        const int  j0A  = j0c + (i << 6);
        const bool hasB = (i + 1 < ntile);
        const bool hasC = (i + 2 < ntile);
        const int  j0B  = j0c + ((hasB ? i + 1 : i) << 6);  // clamp: load-only dup
        const int  j0C  = j0c + ((hasC ? i + 2 : i) << 6);

        Frags fA, fB, fC;
        load_tile(Kh, Vth, hbT, j0A, kloc0, kloc1, quad, vb0, vb1, fA);
        load_tile(Kh, Vth, hbT, j0B, kloc0, kloc1, quad, vb0, vb1, fB);
        load_tile(Kh, Vth, hbT, j0C, kloc0, kloc1, quad, vb0, vb1, fC);

        compute_tile(fA, qfh, qfl, j0A, jminw, jend, quad, mA, lA, oA0, oA1);
        if (hasB)
            compute_tile(fB, qfh, qfl, j0B, jminw, jend, quad, mB, lB, oB0, oB1);
        if (hasC)
            compute_tile(fC, qfh, qfl, j0C, jminw, jend, quad, mC, lC, oC0, oC1);
    }

    // merge the three streams (flash-decoding). Dead streams have m=-1e30 ->
    // weight 0. Stream A always has >=1 live key for a live row (kend>0 and
    // tile 0 starts at j0c < jend).
    const float mm = fmaxf(mA, fmaxf(mB, mC));
    const float wa = __expf(mA - mm), wb = __expf(mB - mm), wc = __expf(mC - mm);
    float l = lA * wa + lB * wb + lC * wc;
    f32x4 o0, o1;
    #pragma unroll
    for (int i = 0; i < 4; i++) {
        o0[i] = oA0[i] * wa + oB0[i] * wb + oC0[i] * wc;
        o1[i] = oA1[i] * wa + oB1[i] * wb + oC1[i] * wc;
    }

    // l holds only this lane's per-tile partials; quads share the same m
    // scale, so the row denominator is the cross-quad sum (R8 bug fix).
    l += __shfl_xor(l, 16);
    l += __shfl_xor(l, 32);

    // write chunk partial: P[bh][qt16][ch][row16][36]
    float* dst = P + ((((size_t)bh * NQT16 + (ig0 >> 4)) * NCH + ch) * 16 + rr) * 36;
    *(f32x4*)(dst + quad * 4)      = o0;   // dims quad*4 .. +3
    *(f32x4*)(dst + 16 + quad * 4) = o1;   // dims 16+quad*4 .. +3
    if (quad == 0) { dst[32] = mm; dst[33] = l; }
}

// ---------------------------------------------------------------------------
// Kernel 3: chunk-merge (flash-decoding) + mean-pool + o-proj + LN + f-proj
// + SiLU. Block per (t, b), 128 threads. LOOP-INTERCHANGED merge: chunk c
// outer (dynamic), force f inner (unrolled) -> 18 independent loads per c
// iteration instead of 6 sequential latency chains. Valid because all 6
// force-rows of time t share jend = 6(t+1) -> identical nch.
// ---------------------------------------------------------------------------
__global__ __launch_bounds__(128) void final_kernel(
    const float* __restrict__ P,
    const float* __restrict__ o_w,    const float* __restrict__ o_b,
    const float* __restrict__ f_ln_w, const float* __restrict__ f_ln_b,
    const float* __restrict__ f_w,    const float* __restrict__ f_b,
    float* __restrict__ out, int C, int NCH)
{
    const int t = blockIdx.x;
    const int b = blockIdx.y;
    const int d = threadIdx.x;     // 0..127
    const int h  = d >> 5;         // head
    const int hd = d & 31;         // dim within head
    const int bh = b * NHH + h;

    __shared__ float ms[HIDD];
    __shared__ float lnbuf[HIDD];
    __shared__ float w1[2], w2[2];

    const int jmax = (t + 1) * NF;
    const int nch  = min(NCH, (jmax + C - 1) / C);

    float M[NF], L[NF], O[NF];
    #pragma unroll
    for (int f = 0; f < NF; f++) { M[f] = -1e30f; L[f] = 0.f; O[f] = 0.f; }

    for (int c = 0; c < nch; c++) {
        #pragma unroll
        for (int f = 0; f < NF; f++) {
            const int row = t * NF + f;
            const float* pr = P + ((((size_t)bh * NQT16 + (row >> 4)) * NCH + c)
                                   * 16 + (row & 15)) * 36;
            const float mc = pr[32], lc = pr[33], oc = pr[hd];
            const float mm = fmaxf(M[f], mc);
            const float sa = __expf(M[f] - mm), sb = __expf(mc - mm);
            O[f] = O[f] * sa + oc * sb;
            L[f] = L[f] * sa + lc * sb;
            M[f] = mm;
        }
    }
    float acc = 0.0f;
    #pragma unroll
    for (int f = 0; f < NF; f++) acc += O[f] / L[f];
    acc *= (1.0f / NF);
    ms[d] = acc;
    __syncthreads();

    float ov = o_b[d];
    for (int k = 0; k < HIDD; k++) ov += ms[k] * o_w[k * HIDD + d];

    float s1 = ov, s2 = ov * ov;
    #pragma unroll
    for (int m = 32; m >= 1; m >>= 1) { s1 += __shfl_xor(s1, m); s2 += __shfl_xor(s2, m); }
    if ((d & 63) == 0) { w1[d >> 6] = s1; w2[d >> 6] = s2; }
    __syncthreads();
    float S1 = w1[0] + w1[1], S2 = w2[0] + w2[1];
    float mu  = S1 * (1.0f / HIDD);
    float var = S2 * (1.0f / HIDD) - mu * mu;
    float r   = rsqrtf(var + EPSF);
    float lnv = (ov - mu) * r * f_ln_w[d] + f_ln_b[d];
    lnbuf[d] = lnv;
    __syncthreads();

    float fv = f_b[d];
    for (int k = 0; k < HIDD; k++) fv += lnbuf[k] * f_w[k * HIDD + d];
    fv = fv / (1.0f + __expf(-fv));

    out[((size_t)(b * TT + t)) * FDD + d] = fv;
}

// ---------------------------------------------------------------------------
extern "C" void kernel_launch(void* const* d_in, const int* in_sizes, int n_in,
                              void* d_out, int out_size, void* d_ws, size_t ws_size,
                              hipStream_t stream)
{
    const float* x      = (const float*)d_in[0];
    const float* g_ln_w = (const float*)d_in[1];
    const float* g_ln_b = (const float*)d_in[2];
    const float* g_w1   = (const float*)d_in[3];
    const float* g_b1   = (const float*)d_in[4];
    const float* g_w2   = (const float*)d_in[5];
    const float* g_b2   = (const float*)d_in[6];
    const float* q_w    = (const float*)d_in[7];
    const float* q_b    = (const float*)d_in[8];
    const float* k_w    = (const float*)d_in[9];
    const float* k_b    = (const float*)d_in[10];
    const float* v_w    = (const float*)d_in[11];
    const float* v_b    = (const float*)d_in[12];
    const float* o_w    = (const float*)d_in[13];
    const float* o_b    = (const float*)d_in[14];
    const float* f_ln_w = (const float*)d_in[15];
    const float* f_ln_b = (const float*)d_in[16];
    const float* f_w    = (const float*)d_in[17];
    const float* f_b    = (const float*)d_in[18];

    const size_t ntok = (size_t)BB * NHH * LL * HDD;     // 786432 bf16 elems/array
    unsigned short* Qh  = (unsigned short*)d_ws;
    unsigned short* Ql  = Qh  + ntok;
    unsigned short* Kh  = Ql  + ntok;
    // region [Kh+ntok, Kh+2*ntok) reserved (was Kl) — layout kept identical
    unsigned short* Vth = Kh + 2 * ntok;
    // region [Vth+ntok, Vth+2*ntok) reserved (was Vtl)
    float* Pw = (float*)(Vth + 2 * ntok);                // split-K partials

    const long long bf_floats = (long long)(6 * ntok) / 2;          // 2359296
    const long long unit = 8LL * NQT16 * 16 * 36;                   // 884736 fl/chunk
    long long avail = (long long)(ws_size / 4) - bf_floats - 4096;  // slack
    int NCH = (int)(avail / unit);
    if (NCH > 8) NCH = 8;
    if (NCH < 1) NCH = 1;
    const int C = 64 * ((LL + 64 * NCH - 1) / (64 * NCH));          // keys/chunk

    gate_qkv_kernel<<<(BB * LL) / 4, 128, 0, stream>>>(
        x, g_ln_w, g_ln_b, g_w1, g_b1, g_w2, g_b2,
        q_w, q_b, k_w, k_b, v_w, v_b, Qh, Ql, Kh, Vth);

    attn_mfma<<<(LL / 64) * NCH * BB * NHH, 256, 0, stream>>>(
        Qh, Ql, Kh, Vth, Pw, C, NCH);

    final_kernel<<<dim3(TT, BB), 128, 0, stream>>>(
        Pw, o_w, o_b, f_ln_w, f_ln_b, f_w, f_b, (float*)d_out, C, NCH);
}